// Round 9
// baseline (462.366 us; speedup 1.0000x reference)
//
#include <hip/hip_runtime.h>
#include <hip/hip_fp16.h>
#include <cstddef>

// ---------------------------------------------------------------------------
// CrystalGNN (SchNet-style). R9: 12 dispatches, scalarized conv payload.
//   memset deg
//   k_pre     : hist deg[dst]++  +  gstart  +  x=emb[ids]  +  hA=x@W1_0+b1_0
//   scan a/b/c -> off[N+1], cursor[N]
//   k_scatter : dst-sorted payload int4{src*64, A, B, 0},
//               A=exp(-1.125 d^2), B=exp(1.5 d); RBF_r=A*B^r*C_r (C_r folded
//               into filter weights) -> conv hot loop transcendental-free
//   per layer : k_conv (gather; k0/k1 + edge index wave-uniform via
//               readfirstlane -> payload goes down the SCALAR pipe as
//               s_load_dwordx4), then k_gemm (h_next = x@W1'+b1', row_gemv)
//   k_poolhead: per-graph mean + two 2-layer MLP heads
// ---------------------------------------------------------------------------

// C_r = exp(-0.5 r^2), r = 0..9
#define RBF_C0 1.0f
#define RBF_C1 0.60653065971f
#define RBF_C2 0.13533528324f
#define RBF_C3 0.011108996538f
#define RBF_C4 3.3546262790e-4f
#define RBF_C5 3.7266531720e-6f
#define RBF_C6 1.5229979745e-8f
#define RBF_C7 2.2897348457e-11f
#define RBF_C8 1.2664165549e-14f
#define RBF_C9 2.5767043600e-18f

__device__ __forceinline__ float softplusf(float v) {
    return fmaxf(v, 0.0f) + log1pf(__expf(-fabsf(v)));
}

__device__ __forceinline__ float row_gemv(const float4* __restrict__ xr,
                                          const float w[64], float bj) {
    float a0 = bj, a1 = 0.f, a2 = 0.f, a3 = 0.f;
#pragma unroll
    for (int q = 0; q < 4; ++q) {
        float4 v0 = xr[4 * q + 0], v1 = xr[4 * q + 1];
        float4 v2 = xr[4 * q + 2], v3 = xr[4 * q + 3];
        a0 = fmaf(v0.x, w[16 * q + 0], a0);  a0 = fmaf(v0.y, w[16 * q + 1], a0);
        a0 = fmaf(v0.z, w[16 * q + 2], a0);  a0 = fmaf(v0.w, w[16 * q + 3], a0);
        a1 = fmaf(v1.x, w[16 * q + 4], a1);  a1 = fmaf(v1.y, w[16 * q + 5], a1);
        a1 = fmaf(v1.z, w[16 * q + 6], a1);  a1 = fmaf(v1.w, w[16 * q + 7], a1);
        a2 = fmaf(v2.x, w[16 * q + 8], a2);  a2 = fmaf(v2.y, w[16 * q + 9], a2);
        a2 = fmaf(v2.z, w[16 * q + 10], a2); a2 = fmaf(v2.w, w[16 * q + 11], a2);
        a3 = fmaf(v3.x, w[16 * q + 12], a3); a3 = fmaf(v3.y, w[16 * q + 13], a3);
        a3 = fmaf(v3.z, w[16 * q + 14], a3); a3 = fmaf(v3.w, w[16 * q + 15], a3);
    }
    return (a0 + a1) + (a2 + a3);
}

__device__ __forceinline__ float filt_ab(const float wp[10], float bj, float A, float B) {
    float P = wp[9];
    P = fmaf(B, P, wp[8]); P = fmaf(B, P, wp[7]); P = fmaf(B, P, wp[6]);
    P = fmaf(B, P, wp[5]); P = fmaf(B, P, wp[4]); P = fmaf(B, P, wp[3]);
    P = fmaf(B, P, wp[2]); P = fmaf(B, P, wp[1]); P = fmaf(B, P, wp[0]);
    return fmaf(A, P, bj);
}

// ---------------- hist + gstart + embed + gemm0 ----------------
__global__ void k_pre(const int* __restrict__ dst, int* __restrict__ deg,
                      const int* __restrict__ batch, int* __restrict__ gstart,
                      const int* __restrict__ ids, const float* __restrict__ emb,
                      const float* __restrict__ W1, const float* __restrict__ b1,
                      float* __restrict__ x, __half* __restrict__ hA,
                      int n_edges, int n_nodes, int n_graphs) {
    int tid = blockIdx.x * blockDim.x + threadIdx.x;
    int nth = gridDim.x * blockDim.x;
    for (int e = tid; e < n_edges; e += nth) atomicAdd(&deg[dst[e]], 1);
    for (int n = tid; n < n_nodes; n += nth) {
        int b = batch[n];
        int prev = (n == 0) ? -1 : batch[n - 1];
        for (int g = prev + 1; g <= b; ++g) gstart[g] = n;
        if (n == n_nodes - 1)
            for (int g = b + 1; g <= n_graphs; ++g) gstart[g] = n_nodes;
    }
    int lane = threadIdx.x & 63;
    int gw = __builtin_amdgcn_readfirstlane(tid >> 6);
    int nw = nth >> 6;
    float w[64];
#pragma unroll
    for (int k = 0; k < 64; ++k) w[k] = W1[k * 64 + lane];
    float bj = b1[lane];
    for (int n = gw; n < n_nodes; n += nw) {
        int id = __builtin_amdgcn_readfirstlane(ids[n]);
        const float4* xr = (const float4*)(emb + id * 64);
        float v = row_gemv(xr, w, bj);
        x[n * 64 + lane] = emb[id * 64 + lane];
        hA[n * 64 + lane] = __float2half(v);
    }
}

// ---------------- scan ----------------
__global__ void k_scana(const int* __restrict__ deg, int* __restrict__ off_,
                        int* __restrict__ bsum, int n) {
    __shared__ int s[256];
    int i = blockIdx.x * 256 + threadIdx.x;
    int v = (i < n) ? deg[i] : 0;
    s[threadIdx.x] = v;
    __syncthreads();
    for (int off = 1; off < 256; off <<= 1) {
        int t = (threadIdx.x >= off) ? s[threadIdx.x - off] : 0;
        __syncthreads();
        s[threadIdx.x] += t;
        __syncthreads();
    }
    if (i < n) off_[i + 1] = s[threadIdx.x];
    if (threadIdx.x == 255) bsum[blockIdx.x] = s[255];
}

__global__ void k_scanb(int* __restrict__ bsum, int nb) {
    __shared__ int s[256];
    int v = ((int)threadIdx.x < nb) ? bsum[threadIdx.x] : 0;
    s[threadIdx.x] = v;
    __syncthreads();
    for (int off = 1; off < 256; off <<= 1) {
        int t = (threadIdx.x >= off) ? s[threadIdx.x - off] : 0;
        __syncthreads();
        s[threadIdx.x] += t;
        __syncthreads();
    }
    if ((int)threadIdx.x < nb) bsum[threadIdx.x] = s[threadIdx.x] - v;  // exclusive
}

__global__ void k_scanc(const int* __restrict__ deg, const int* __restrict__ bsum,
                        int* __restrict__ off_, int* __restrict__ cursor, int n) {
    int i = blockIdx.x * blockDim.x + threadIdx.x;
    if (i < n) {
        int incl = off_[i + 1] + bsum[i >> 8];
        off_[i + 1] = incl;
        cursor[i] = incl - deg[i];
    }
    if (i == 0) off_[0] = 0;
}

// ---------------- scatter: payload {src*64, A, B, 0} ----------------
__global__ void k_scatter(const int* __restrict__ src, const int* __restrict__ dst,
                          const float* __restrict__ dist, int* __restrict__ cursor,
                          int4* __restrict__ psort, int n_edges) {
    int e = blockIdx.x * blockDim.x + threadIdx.x;
    if (e >= n_edges) return;
    int t = dst[e];
    int pos = atomicAdd(&cursor[t], 1);
    float d = dist[e];
    float A = __expf(-1.125f * d * d);
    float B = __expf(1.5f * d);
    psort[pos] = make_int4(src[e] << 6, __float_as_int(A), __float_as_int(B), 0);
}

// ---------------- gemm: h = x@W1_l + b1_l ----------------
__global__ __launch_bounds__(256, 4) void k_gemm(
        const float* __restrict__ X, const float* __restrict__ W,
        const float* __restrict__ bias, __half* __restrict__ Y, int n_nodes) {
    int lane = threadIdx.x & 63;
    int gw = __builtin_amdgcn_readfirstlane((blockIdx.x * blockDim.x + threadIdx.x) >> 6);
    int nw = (gridDim.x * blockDim.x) >> 6;
    float w[64];
#pragma unroll
    for (int k = 0; k < 64; ++k) w[k] = W[k * 64 + lane];
    float bj = bias[lane];
    for (int n = gw; n < n_nodes; n += nw) {
        const float4* xr = (const float4*)(X + n * 64);
        Y[n * 64 + lane] = __float2half(row_gemv(xr, w, bj));
    }
}

// ---------------- conv ----------------
__global__ __launch_bounds__(256, 6) void k_conv(
        const int4* __restrict__ ps, const int* __restrict__ off,
        const __half* __restrict__ h,
        const float* __restrict__ We, const float* __restrict__ be,
        const float* __restrict__ W2, const float* __restrict__ b2,
        float* __restrict__ x, int n_nodes) {
    int lane = threadIdx.x & 63;
    int gw = __builtin_amdgcn_readfirstlane((blockIdx.x * blockDim.x + threadIdx.x) >> 6);
    int nw = (gridDim.x * blockDim.x) >> 6;

    const float C[10] = {RBF_C0, RBF_C1, RBF_C2, RBF_C3, RBF_C4,
                         RBF_C5, RBF_C6, RBF_C7, RBF_C8, RBF_C9};
    float wp[10];
#pragma unroll
    for (int r = 0; r < 10; ++r) wp[r] = We[r * 64 + lane] * C[r];
    float bj  = be[lane];
    float b2j = b2[lane];

    for (int n = gw; n < n_nodes; n += nw) {
        // wave-uniform edge range -> SGPRs, so ps[k+i] scalarizes to s_load
        int k0 = __builtin_amdgcn_readfirstlane(off[n]);
        int k1 = __builtin_amdgcn_readfirstlane(off[n + 1]);
        float acc = 0.0f;
        int k = k0;
        for (; k + 8 <= k1; k += 8) {   // 8 gathers in flight
            int4 p0 = ps[k + 0], p1 = ps[k + 1], p2 = ps[k + 2], p3 = ps[k + 3];
            int4 p4 = ps[k + 4], p5 = ps[k + 5], p6 = ps[k + 6], p7 = ps[k + 7];
            float g0 = __half2float(h[p0.x + lane]);
            float g1 = __half2float(h[p1.x + lane]);
            float g2 = __half2float(h[p2.x + lane]);
            float g3 = __half2float(h[p3.x + lane]);
            float g4 = __half2float(h[p4.x + lane]);
            float g5 = __half2float(h[p5.x + lane]);
            float g6 = __half2float(h[p6.x + lane]);
            float g7 = __half2float(h[p7.x + lane]);
            acc = fmaf(g0, filt_ab(wp, bj, __int_as_float(p0.y), __int_as_float(p0.z)), acc);
            acc = fmaf(g1, filt_ab(wp, bj, __int_as_float(p1.y), __int_as_float(p1.z)), acc);
            acc = fmaf(g2, filt_ab(wp, bj, __int_as_float(p2.y), __int_as_float(p2.z)), acc);
            acc = fmaf(g3, filt_ab(wp, bj, __int_as_float(p3.y), __int_as_float(p3.z)), acc);
            acc = fmaf(g4, filt_ab(wp, bj, __int_as_float(p4.y), __int_as_float(p4.z)), acc);
            acc = fmaf(g5, filt_ab(wp, bj, __int_as_float(p5.y), __int_as_float(p5.z)), acc);
            acc = fmaf(g6, filt_ab(wp, bj, __int_as_float(p6.y), __int_as_float(p6.z)), acc);
            acc = fmaf(g7, filt_ab(wp, bj, __int_as_float(p7.y), __int_as_float(p7.z)), acc);
        }
        for (; k + 4 <= k1; k += 4) {
            int4 p0 = ps[k + 0], p1 = ps[k + 1], p2 = ps[k + 2], p3 = ps[k + 3];
            float g0 = __half2float(h[p0.x + lane]);
            float g1 = __half2float(h[p1.x + lane]);
            float g2 = __half2float(h[p2.x + lane]);
            float g3 = __half2float(h[p3.x + lane]);
            acc = fmaf(g0, filt_ab(wp, bj, __int_as_float(p0.y), __int_as_float(p0.z)), acc);
            acc = fmaf(g1, filt_ab(wp, bj, __int_as_float(p1.y), __int_as_float(p1.z)), acc);
            acc = fmaf(g2, filt_ab(wp, bj, __int_as_float(p2.y), __int_as_float(p2.z)), acc);
            acc = fmaf(g3, filt_ab(wp, bj, __int_as_float(p3.y), __int_as_float(p3.z)), acc);
        }
        for (; k < k1; ++k) {
            int4 p = ps[k];
            float g = __half2float(h[p.x + lane]);
            acc = fmaf(g, filt_ab(wp, bj, __int_as_float(p.y), __int_as_float(p.z)), acc);
        }
        // x_new = softplus(x + b2 + acc @ W2)
        float o0 = b2j + x[n * 64 + lane];
        float o1 = 0.f, o2 = 0.f, o3 = 0.f;
#pragma unroll 4
        for (int kk = 0; kk < 16; ++kk) {
            o0 = fmaf(__shfl(acc, kk),      W2[(kk)      * 64 + lane], o0);
            o1 = fmaf(__shfl(acc, kk + 16), W2[(kk + 16) * 64 + lane], o1);
            o2 = fmaf(__shfl(acc, kk + 32), W2[(kk + 32) * 64 + lane], o2);
            o3 = fmaf(__shfl(acc, kk + 48), W2[(kk + 48) * 64 + lane], o3);
        }
        x[n * 64 + lane] = softplusf((o0 + o1) + (o2 + o3));
    }
}

// ---------------- fused pool + head: one block per graph ----------------
__global__ void k_poolhead(const float* __restrict__ x, const int* __restrict__ gstart,
                           const float* __restrict__ Ws, const float* __restrict__ bs,
                           const float* __restrict__ Wbg1, const float* __restrict__ bbg1,
                           const float* __restrict__ Wbg2, const float* __restrict__ bbg2,
                           const float* __restrict__ Weh1, const float* __restrict__ beh1,
                           const float* __restrict__ Weh2, const float* __restrict__ beh2,
                           float* __restrict__ out, int n_graphs) {
    __shared__ float red[256];
    __shared__ float c[64];
    __shared__ float h1[128];
    int g = blockIdx.x;
    int t = threadIdx.x, j = t & 63, part = t >> 6;
    int s0 = gstart[g], s1 = gstart[g + 1];
    float acc = 0.0f;
    for (int n = s0 + part; n < s1; n += 4) acc += x[n * 64 + j];
    red[t] = acc;
    __syncthreads();
    if (part == 0)
        c[j] = (red[j] + red[64 + j] + red[128 + j] + red[192 + j]) /
               fmaxf((float)(s1 - s0), 1.0f);
    __syncthreads();
    if (t < 128) {
        float av = bs[t];
#pragma unroll 8
        for (int k = 0; k < 64; ++k) av = fmaf(c[k], Ws[k * 128 + t], av);
        h1[t] = fmaxf(av, 0.0f);
    }
    __syncthreads();
    if (t < 128) {
        const float* W1p = (t < 64) ? Wbg1 : Weh1;
        const float* b1p = (t < 64) ? bbg1 : beh1;
        const float* W2p = (t < 64) ? Wbg2 : Weh2;
        float b2v = (t < 64) ? bbg2[0] : beh2[0];
        int ln = t & 63;
        float a2 = b1p[ln];
#pragma unroll 8
        for (int k = 0; k < 128; ++k) a2 = fmaf(h1[k], W1p[k * 64 + ln], a2);
        a2 = fmaxf(a2, 0.0f);
        float pr = a2 * W2p[ln];
#pragma unroll
        for (int off = 32; off > 0; off >>= 1) pr += __shfl_down(pr, off);
        if (ln == 0) out[(t < 64 ? 0 : n_graphs) + g] = pr + b2v;
    }
}

extern "C" void kernel_launch(void* const* d_in, const int* in_sizes, int n_in,
                              void* d_out, int out_size, void* d_ws, size_t ws_size,
                              hipStream_t stream) {
    const int*   x_ids = (const int*)d_in[0];
    const int*   eidx  = (const int*)d_in[1];
    const float* eattr = (const float*)d_in[2];
    const int*   batch = (const int*)d_in[3];
    const float* emb   = (const float*)d_in[4];
    const float* W1    = (const float*)d_in[5];
    const float* b1    = (const float*)d_in[6];
    const float* We    = (const float*)d_in[7];
    const float* be    = (const float*)d_in[8];
    const float* W2    = (const float*)d_in[9];
    const float* b2    = (const float*)d_in[10];
    const float* Ws_   = (const float*)d_in[11];
    const float* bs_   = (const float*)d_in[12];
    const float* Wbg1  = (const float*)d_in[13];
    const float* bbg1  = (const float*)d_in[14];
    const float* Wbg2  = (const float*)d_in[15];
    const float* bbg2  = (const float*)d_in[16];
    const float* Weh1  = (const float*)d_in[17];
    const float* beh1  = (const float*)d_in[18];
    const float* Weh2  = (const float*)d_in[19];
    const float* beh2  = (const float*)d_in[20];

    int n_nodes  = in_sizes[0];
    int n_edges  = in_sizes[2];
    int n_graphs = out_size / 2;
    const int* src = eidx;
    const int* dst = eidx + n_edges;

    char* p = (char*)d_ws;
    float* x     = (float*)p;   p += (size_t)n_nodes * 64 * sizeof(float);
    __half* hA   = (__half*)p;  p += (size_t)n_nodes * 64 * sizeof(__half);
    __half* hB   = (__half*)p;  p += (size_t)n_nodes * 64 * sizeof(__half);
    int4* psort  = (int4*)p;    p += (size_t)n_edges * sizeof(int4);
    int* deg     = (int*)p;     p += (size_t)n_nodes * sizeof(int);
    int* off_    = (int*)p;     p += (size_t)(n_nodes + 1) * sizeof(int);
    int* cursor  = (int*)p;     p += (size_t)n_nodes * sizeof(int);
    int* bsum    = (int*)p;     p += 256 * sizeof(int);
    int* gstart  = (int*)p;     p += (size_t)(n_graphs + 1) * sizeof(int);
    float* out   = (float*)d_out;

    int nchunks = (n_nodes + 255) / 256;
    int nbE = (n_edges + 255) / 256;
    int nbN = (n_nodes + 255) / 256;

    hipMemsetAsync(deg, 0, (size_t)n_nodes * sizeof(int), stream);
    k_pre<<<nbE, 256, 0, stream>>>(dst, deg, batch, gstart, x_ids, emb, W1, b1,
                                   x, hA, n_edges, n_nodes, n_graphs);
    k_scana<<<nchunks, 256, 0, stream>>>(deg, off_, bsum, n_nodes);
    k_scanb<<<1, 256, 0, stream>>>(bsum, nchunks);
    k_scanc<<<nbN, 256, 0, stream>>>(deg, bsum, off_, cursor, n_nodes);
    k_scatter<<<nbE, 256, 0, stream>>>(src, dst, eattr, cursor, psort, n_edges);

    k_conv<<<4096, 256, 0, stream>>>(psort, off_, hA, We, be, W2, b2, x, n_nodes);
    k_gemm<<<1024, 256, 0, stream>>>(x, W1 + 4096, b1 + 64, hB, n_nodes);
    k_conv<<<4096, 256, 0, stream>>>(psort, off_, hB, We + 640, be + 64,
                                     W2 + 4096, b2 + 64, x, n_nodes);
    k_gemm<<<1024, 256, 0, stream>>>(x, W1 + 8192, b1 + 128, hA, n_nodes);
    k_conv<<<4096, 256, 0, stream>>>(psort, off_, hA, We + 1280, be + 128,
                                     W2 + 8192, b2 + 128, x, n_nodes);

    k_poolhead<<<n_graphs, 256, 0, stream>>>(x, gstart, Ws_, bs_, Wbg1, bbg1, Wbg2, bbg2,
                                             Weh1, beh1, Weh2, beh2, out, n_graphs);
}